// Round 1
// baseline (884.756 us; speedup 1.0000x reference)
//
#include <hip/hip_runtime.h>
#include <stdint.h>

// Problem constants (B=8, S=1024, D=256, K=16384)
#define N_ROWS 8192
#define D_DIM  256
#define K_CENT 16384

// d_out layout (float32):
//   [0, 2097152)                      quantized (8,1024,256)
//   [2097152, 2105344)                cluster_ids as float (8,1024)
//   [2105344, 2105344+134217728)      dist (8192,16384)

// d_ws layout:
//   [0, 8192) f32          xnorm
//   [8192, 24576) f32      cnorm
//   byte 98304: 8192 x u64 rowkeys (min-dist key per row)

// Monotone order-preserving float->uint mapping
__device__ __forceinline__ uint32_t fkey(float f) {
    uint32_t b = __float_as_uint(f);
    return (b & 0x80000000u) ? ~b : (b | 0x80000000u);
}

__global__ void init_keys(unsigned long long* __restrict__ keys) {
    int i = blockIdx.x * blockDim.x + threadIdx.x;
    if (i < N_ROWS) keys[i] = 0xFFFFFFFFFFFFFFFFull;
}

// One wave per row; 64 lanes x float4 = 256 floats exactly.
__global__ void norms_kernel(const float* __restrict__ feat,
                             const float* __restrict__ cent,
                             float* __restrict__ xnorm,
                             float* __restrict__ cnorm) {
    int gtid = blockIdx.x * blockDim.x + threadIdx.x;
    int wave = gtid >> 6;
    int lane = gtid & 63;
    if (wave >= N_ROWS + K_CENT) return;
    const float* src = (wave < N_ROWS) ? (feat + (size_t)wave * D_DIM)
                                       : (cent + (size_t)(wave - N_ROWS) * D_DIM);
    float4 v = ((const float4*)src)[lane];
    float s = v.x * v.x + v.y * v.y + v.z * v.z + v.w * v.w;
    #pragma unroll
    for (int off = 32; off >= 1; off >>= 1) s += __shfl_xor(s, off);
    if (lane == 0) {
        if (wave < N_ROWS) xnorm[wave] = s;
        else cnorm[wave - N_ROWS] = s;
    }
}

#define BM 128
#define BN 64
#define BK 32

// dist[n][k] = (xnorm[n] - 2*dot(x_n, c_k)) + cnorm[k]   (np op order)
__global__ __launch_bounds__(256, 2)
void dist_gemm(const float* __restrict__ A,      // 8192 x 256
               const float* __restrict__ B,      // 16384 x 256
               const float* __restrict__ xnorm,
               const float* __restrict__ cnorm,
               float* __restrict__ dist,         // 8192 x 16384
               unsigned long long* __restrict__ rowkeys) {
    __shared__ float As[BK][BM + 4];   // transposed [k][row], pad 4
    __shared__ float Bs[BK][BN + 4];

    const int tid = threadIdx.x;
    const int tx = tid & 15;
    const int ty = tid >> 4;
    const int row0 = blockIdx.x * BM;
    const int col0 = blockIdx.y * BN;

    float acc[8][4];
    #pragma unroll
    for (int i = 0; i < 8; ++i)
        #pragma unroll
        for (int j = 0; j < 4; ++j) acc[i][j] = 0.f;

    const float4* A4 = (const float4*)A;  // row stride = 64 float4
    const float4* B4 = (const float4*)B;

    for (int kt = 0; kt < D_DIM / BK; ++kt) {
        // Stage A tile: 128 rows x 32 k = 1024 float4, 4 per thread
        #pragma unroll
        for (int j = 0; j < 4; ++j) {
            int f = tid + 256 * j;
            int r = f >> 3;       // 0..127
            int kq = f & 7;       // float4 index within the 32-k chunk
            float4 a = A4[(size_t)(row0 + r) * 64 + kt * 8 + kq];
            As[kq * 4 + 0][r] = a.x;
            As[kq * 4 + 1][r] = a.y;
            As[kq * 4 + 2][r] = a.z;
            As[kq * 4 + 3][r] = a.w;
        }
        // Stage B tile: 64 rows x 32 k = 512 float4, 2 per thread
        #pragma unroll
        for (int j = 0; j < 2; ++j) {
            int f = tid + 256 * j;
            int r = f >> 3;       // 0..63
            int kq = f & 7;
            float4 b = B4[(size_t)(col0 + r) * 64 + kt * 8 + kq];
            Bs[kq * 4 + 0][r] = b.x;
            Bs[kq * 4 + 1][r] = b.y;
            Bs[kq * 4 + 2][r] = b.z;
            Bs[kq * 4 + 3][r] = b.w;
        }
        __syncthreads();

        #pragma unroll
        for (int kk = 0; kk < BK; ++kk) {
            float4 a0 = *(const float4*)&As[kk][8 * ty];
            float4 a1 = *(const float4*)&As[kk][8 * ty + 4];
            float4 b  = *(const float4*)&Bs[kk][4 * tx];
            float av[8] = {a0.x, a0.y, a0.z, a0.w, a1.x, a1.y, a1.z, a1.w};
            float bv[4] = {b.x, b.y, b.z, b.w};
            #pragma unroll
            for (int i = 0; i < 8; ++i)
                #pragma unroll
                for (int j = 0; j < 4; ++j)
                    acc[i][j] = fmaf(av[i], bv[j], acc[i][j]);
        }
        __syncthreads();
    }

    // Epilogue: dist write + per-row argmin via atomicMin on packed key
    float cn[4];
    #pragma unroll
    for (int j = 0; j < 4; ++j) cn[j] = cnorm[col0 + 4 * tx + j];

    #pragma unroll
    for (int i = 0; i < 8; ++i) {
        int row = row0 + 8 * ty + i;
        float xn = xnorm[row];
        float4 dv;
        dv.x = (xn - 2.f * acc[i][0]) + cn[0];
        dv.y = (xn - 2.f * acc[i][1]) + cn[1];
        dv.z = (xn - 2.f * acc[i][2]) + cn[2];
        dv.w = (xn - 2.f * acc[i][3]) + cn[3];
        ((float4*)(dist + (size_t)row * K_CENT + col0 + 4 * tx))[0] = dv;

        int cbase = col0 + 4 * tx;
        float mv = dv.x; int mi = cbase;
        if (dv.y < mv) { mv = dv.y; mi = cbase + 1; }
        if (dv.z < mv) { mv = dv.z; mi = cbase + 2; }
        if (dv.w < mv) { mv = dv.w; mi = cbase + 3; }

        // reduce across the 16 tx lanes (same ty -> consecutive lanes)
        #pragma unroll
        for (int off = 8; off >= 1; off >>= 1) {
            float ov = __shfl_down(mv, off);
            int   oi = __shfl_down(mi, off);
            if (ov < mv || (ov == mv && oi < mi)) { mv = ov; mi = oi; }
        }
        if (tx == 0) {
            unsigned long long key =
                ((unsigned long long)fkey(mv) << 32) | (unsigned)mi;
            atomicMin(&rowkeys[row], key);
        }
    }
}

// One block (64 threads) per row: write id as float + gather codebook row.
__global__ void finalize_kernel(const unsigned long long* __restrict__ rowkeys,
                                const float* __restrict__ cent,
                                float* __restrict__ quant,
                                float* __restrict__ ids) {
    int row = blockIdx.x;
    int lane = threadIdx.x;
    unsigned idx = (unsigned)(rowkeys[row] & 0xFFFFFFFFu);
    if (lane == 0) ids[row] = (float)idx;
    float4 v = ((const float4*)(cent + (size_t)idx * D_DIM))[lane];
    ((float4*)(quant + (size_t)row * D_DIM))[lane] = v;
}

extern "C" void kernel_launch(void* const* d_in, const int* in_sizes, int n_in,
                              void* d_out, int out_size, void* d_ws, size_t ws_size,
                              hipStream_t stream) {
    const float* feat = (const float*)d_in[0];   // 8192 x 256
    const float* cent = (const float*)d_in[1];   // 16384 x 256

    float* out = (float*)d_out;
    float* quant = out;                              // 2097152
    float* ids   = out + 2097152;                    // 8192
    float* dist  = out + 2105344;                    // 8192*16384

    float* xnorm = (float*)d_ws;
    float* cnorm = xnorm + N_ROWS;
    unsigned long long* rowkeys =
        (unsigned long long*)((char*)d_ws + (N_ROWS + K_CENT) * sizeof(float));

    // init rowkeys (must happen every call — deterministic)
    init_keys<<<(N_ROWS + 255) / 256, 256, 0, stream>>>(rowkeys);

    // norms: one wave per row, (8192+16384) waves, 4 waves/block
    {
        int waves = N_ROWS + K_CENT;
        int blocks = (waves * 64 + 255) / 256;
        norms_kernel<<<blocks, 256, 0, stream>>>(feat, cent, xnorm, cnorm);
    }

    // dist GEMM + fused row-min
    {
        dim3 grid(N_ROWS / BM, K_CENT / BN);   // 64 x 256
        dist_gemm<<<grid, 256, 0, stream>>>(feat, cent, xnorm, cnorm, dist, rowkeys);
    }

    // finalize: ids + gather
    finalize_kernel<<<N_ROWS, 64, 0, stream>>>(rowkeys, cent, quant, ids);
}